// Round 8
// baseline (34.076 us; speedup 1.0000x reference)
//
#include <hip/hip_runtime.h>

#define H 32
#define C 64
#define K 15
#define SIGMA 0.3f
#define WAVES 2          // waves per block (block = 128)
#define QPW 4            // queries per wave

__global__ __launch_bounds__(128) void kpconv_kernel(
    const float* __restrict__ q_pts,
    const float* __restrict__ s_pts,
    const float* __restrict__ s_feats,
    const int*   __restrict__ inds,
    const float* __restrict__ weights,
    const float* __restrict__ kpts,
    float*       __restrict__ out,
    int N)
{
    // padded row (34 float2 = 272 B): q-rows stay 16B-aligned, banks spread
    __shared__ float2 list[WAVES][QPW][34];   // ~2.2 KB

    const int tid  = threadIdx.x;
    const int wave = tid >> 6;
    const int lane = tid & 63;
    const int half = lane >> 5;          // query within a pass
    const int hl   = lane & 31;          // neighbor slot

    // wave-uniform kernel points -> SGPRs via s_load
    float kp[K * 3];
    #pragma unroll
    for (int i = 0; i < K * 3; ++i) kp[i] = kpts[i];

    const int qBase = (blockIdx.x * WAVES + wave) * QPW;

    // ---- Load stage: BOTH passes' chains issued together ----
    const int m0 = qBase + half;         // pass-0 query (lanes 0-31 / 32-63)
    const int m1 = qBase + 2 + half;     // pass-1 query
    const int idx0 = (m0 < N) ? inds[m0 * H + hl] : -1;   // 256B coalesced
    const int idx1 = (m1 < N) ? inds[m1 * H + hl] : -1;   // 256B coalesced
    const bool ok0 = (idx0 >= 0) && (idx0 < N);
    const bool ok1 = (idx1 >= 0) && (idx1 < N);
    const int ia0 = ok0 ? idx0 : 0;
    const int ia1 = ok1 ? idx1 : 0;
    const float sx0 = s_pts[ia0 * 3 + 0], sy0 = s_pts[ia0 * 3 + 1], sz0 = s_pts[ia0 * 3 + 2];
    const float sx1 = s_pts[ia1 * 3 + 0], sy1 = s_pts[ia1 * 3 + 1], sz1 = s_pts[ia1 * 3 + 2];
    float qx0 = 0.f, qy0 = 0.f, qz0 = 0.f, qx1 = 0.f, qy1 = 0.f, qz1 = 0.f;
    if (m0 < N) { qx0 = q_pts[m0 * 3 + 0]; qy0 = q_pts[m0 * 3 + 1]; qz0 = q_pts[m0 * 3 + 2]; }
    if (m1 < N) { qx1 = q_pts[m1 * 3 + 0]; qy1 = q_pts[m1 * 3 + 1]; qz1 = q_pts[m1 * 3 + 2]; }

    // ---- Phase A: both argmins interleaved (independent VALU chains) ----
    const float nx0 = sx0 - qx0, ny0 = sy0 - qy0, nz0 = sz0 - qz0;
    const float nx1 = sx1 - qx1, ny1 = sy1 - qy1, nz1 = sz1 - qz1;
    float best0 = 1e30f, best1 = 1e30f;
    int   kb0 = 0, kb1 = 0;
    #pragma unroll
    for (int k = 0; k < K; ++k) {        // per-element math identical to R6
        const float ax = nx0 - kp[k * 3 + 0];
        const float ay = ny0 - kp[k * 3 + 1];
        const float az = nz0 - kp[k * 3 + 2];
        const float d20 = ax * ax + ay * ay + az * az;
        const float bx = nx1 - kp[k * 3 + 0];
        const float by = ny1 - kp[k * 3 + 1];
        const float bz = nz1 - kp[k * 3 + 2];
        const float d21 = bx * bx + by * by + bz * bz;
        if (d20 < best0) { best0 = d20; kb0 = k; }
        if (d21 < best1) { best1 = d21; kb1 = k; }
    }
    float infl0 = 1.0f - __builtin_amdgcn_sqrtf(best0) * (1.0f / SIGMA);
    float infl1 = 1.0f - __builtin_amdgcn_sqrtf(best1) * (1.0f / SIGMA);
    if (infl0 < 0.0f || !ok0) infl0 = 0.0f;
    if (infl1 < 0.0f || !ok1) infl1 = 0.0f;
    const int packed0 = ia0 | (kb0 << 20);
    const int packed1 = ia1 | (kb1 << 20);

    // ---- compact actives into wave-private LDS lists ----
    int c0, c1, c2, c3;
    {
        const unsigned long long ball = __ballot(infl0 > 0.0f);
        const unsigned int lo = (unsigned int)ball, hi = (unsigned int)(ball >> 32);
        const unsigned int maskH = half ? hi : lo;
        const int rank = __popc(maskH & ((1u << hl) - 1u));
        if (infl0 > 0.0f)
            list[wave][half][rank] = make_float2(__int_as_float(packed0), infl0);
        c0 = __popc(lo); c1 = __popc(hi);
    }
    {
        const unsigned long long ball = __ballot(infl1 > 0.0f);
        const unsigned int lo = (unsigned int)ball, hi = (unsigned int)(ball >> 32);
        const unsigned int maskH = half ? hi : lo;
        const int rank = __popc(maskH & ((1u << hl) - 1u));
        if (infl1 > 0.0f)
            list[wave][2 + half][rank] = make_float2(__int_as_float(packed1), infl1);
        c2 = __popc(lo); c3 = __popc(hi);
    }
    // same-wave LDS RAW: DS pipe is in-order per wave; no barrier needed.

    // ---- Phase B: quarter-wave per query, float4 channels, 2 pops/iter ----
    const int q  = lane >> 4;            // which of the 4 queries
    const int ql = lane & 15;            // channel group (4 channels)
    const int cq = (q < 2) ? (q == 0 ? c0 : c1) : (q == 2 ? c2 : c3);
    int maxc = c0 > c1 ? c0 : c1;
    if (c2 > maxc) maxc = c2;
    if (c3 > maxc) maxc = c3;

    float4 acc = make_float4(0.0f, 0.0f, 0.0f, 0.0f);
    for (int i = 0; i < maxc; i += 2) {
        if (i < cq) {
            const float4 pf = *(const float4*)&list[wave][q][i];  // 16B aligned
            const int   p0   = __float_as_int(pf.x);
            const float f0   = pf.y;
            const bool  has1 = (i + 1) < cq;
            const int   p1   = has1 ? __float_as_int(pf.z) : 0;   // row 0: hot line
            const float f1   = has1 ? pf.w : 0.0f;
            const float4 a0 = *(const float4*)(s_feats + (size_t)(p0 & 0xFFFFF) * C + ql * 4);
            const float4 w0 = *(const float4*)(weights + (p0 >> 20) * C + ql * 4);
            const float4 a1 = *(const float4*)(s_feats + (size_t)(p1 & 0xFFFFF) * C + ql * 4);
            const float4 w1 = *(const float4*)(weights + (p1 >> 20) * C + ql * 4);
            acc.x += a0.x * w0.x * f0;  acc.y += a0.y * w0.y * f0;
            acc.z += a0.z * w0.z * f0;  acc.w += a0.w * w0.w * f0;
            acc.x += a1.x * w1.x * f1;  acc.y += a1.y * w1.y * f1;
            acc.z += a1.z * w1.z * f1;  acc.w += a1.w * w1.w * f1;
        }
    }

    const int mq = qBase + q;
    if (mq < N)
        *(float4*)(out + (size_t)mq * C + ql * 4) = acc;   // 256B per query
}

extern "C" void kernel_launch(void* const* d_in, const int* in_sizes, int n_in,
                              void* d_out, int out_size, void* d_ws, size_t ws_size,
                              hipStream_t stream) {
    const float* q_pts   = (const float*)d_in[0];
    const float* s_pts   = (const float*)d_in[1];
    const float* s_feats = (const float*)d_in[2];
    const int*   inds    = (const int*)d_in[3];
    const float* weights = (const float*)d_in[4];
    const float* kpts    = (const float*)d_in[5];
    float* out = (float*)d_out;

    const int N = in_sizes[0] / 3;               // q_pts is (N,3)
    const int qpb = WAVES * QPW;                 // 8 queries per block
    const int blocks = (N + qpb - 1) / qpb;      // 12500
    kpconv_kernel<<<blocks, 128, 0, stream>>>(q_pts, s_pts, s_feats, inds,
                                              weights, kpts, out, N);
}